// Round 5
// baseline (361.840 us; speedup 1.0000x reference)
//
#include <hip/hip_runtime.h>
#include <hip/hip_bf16.h>

#define FDIM 128
#define TMB 16   // nodes per block
#define TMH 8    // nodes per half-block (128 threads)
#define NRBF 20
#define PI_OVER_CUT 0.6283185307179586f  // pi / 5.0

static __device__ __forceinline__ unsigned short bf16_bits(float x) {
    unsigned u = __float_as_uint(x);
    unsigned r = u + 0x7FFF + ((u >> 16) & 1);   // round-to-nearest-even
    return (unsigned short)(r >> 16);
}
static __device__ __forceinline__ float bf16_f(unsigned short b) {
    return __uint_as_float(((unsigned)b) << 16);
}

// Per-node fused kernel: h = silu(s@W1+b1); s_out = h@W2+b2 (cols [0,128) and
// [256,384)); A = filt_g*ccut*s_out_g; M = filt_m*ccut*s_out_m.
// Epilogue packs per-(node,channel) record VM = {A*v0, A*v1, A*v2, M} so the
// edge gather is a single dwordx4 stream (V depends only on src!).
__global__ __launch_bounds__(256) void node_kernel(
    const float* __restrict__ node_s, const float* __restrict__ node_vec,
    const float* __restrict__ edge_dis,
    const float* __restrict__ W1, const float* __restrict__ b1,
    const float* __restrict__ W2, const float* __restrict__ b2,
    const float* __restrict__ Wf, const float* __restrict__ bf,
    float4* __restrict__ VMf, ushort4* __restrict__ VMh, int use_f32, int N)
{
    __shared__ float sh_s[TMB][FDIM];   // node_s tile; overwritten with h
    __shared__ float sh_rbf[TMB][NRBF];
    __shared__ float sh_ccut[TMB];

    const int tid = threadIdx.x;
    const int g   = tid >> 7;     // 0/1: which half-block
    const int c   = tid & 127;    // output column
    const int n0  = blockIdx.x * TMB;
    const int m0  = g * TMH;

    {
        const float4* g4 = (const float4*)(node_s + (size_t)n0 * FDIM);
        float4* s4 = (float4*)&sh_s[0][0];
        #pragma unroll
        for (int i = tid; i < TMB * FDIM / 4; i += 256) s4[i] = g4[i];
    }
    // rbf: 16 nodes x 20 k = 320 entries > 256 threads -> strided
    for (int idx = tid; idx < TMB * NRBF; idx += 256) {
        int m = idx / NRBF, k = idx - m * NRBF;
        float dd = edge_dis[n0 + m];
        sh_rbf[m][k] = sinf((float)(k + 1) * PI_OVER_CUT * dd) / dd;
    }
    if (tid < TMB) {
        float dd = edge_dis[n0 + tid];
        sh_ccut[tid] = (dd <= 5.0f) ? 0.5f * (cosf(PI_OVER_CUT * dd) + 1.0f) : 0.0f;
    }
    __syncthreads();

    float acc[TMH];

    // ---- GEMM1: h = silu(s @ W1 + b1) ----
    #pragma unroll
    for (int m = 0; m < TMH; m++) acc[m] = 0.0f;
    for (int k = 0; k < FDIM; k += 4) {
        float w0 = W1[(k + 0) * FDIM + c];
        float w1 = W1[(k + 1) * FDIM + c];
        float w2 = W1[(k + 2) * FDIM + c];
        float w3 = W1[(k + 3) * FDIM + c];
        #pragma unroll
        for (int m = 0; m < TMH; m++) {
            float4 s4 = *(const float4*)&sh_s[m0 + m][k];
            acc[m] = fmaf(s4.x, w0, fmaf(s4.y, w1, fmaf(s4.z, w2, fmaf(s4.w, w3, acc[m]))));
        }
    }
    __syncthreads();
    {
        float bb = b1[c];
        #pragma unroll
        for (int m = 0; m < TMH; m++) {
            float x = acc[m] + bb;
            sh_s[m0 + m][c] = x / (1.0f + expf(-x));
        }
    }
    __syncthreads();

    // ---- GEMM2 pass A: cols [0,128) -> vector gate A (kept in regs) ----
    #pragma unroll
    for (int m = 0; m < TMH; m++) acc[m] = 0.0f;
    for (int k = 0; k < FDIM; k += 4) {
        float w0 = W2[(k + 0) * 384 + c];
        float w1 = W2[(k + 1) * 384 + c];
        float w2 = W2[(k + 2) * 384 + c];
        float w3 = W2[(k + 3) * 384 + c];
        #pragma unroll
        for (int m = 0; m < TMH; m++) {
            float4 s4 = *(const float4*)&sh_s[m0 + m][k];
            acc[m] = fmaf(s4.x, w0, fmaf(s4.y, w1, fmaf(s4.z, w2, fmaf(s4.w, w3, acc[m]))));
        }
    }
    float aval[TMH];
    {
        float wf[NRBF];
        #pragma unroll
        for (int k = 0; k < NRBF; k++) wf[k] = Wf[k * 384 + c];
        float bft = bf[c];
        float b2t = b2[c];
        #pragma unroll
        for (int m = 0; m < TMH; m++) {
            float fg = bft;
            #pragma unroll
            for (int k = 0; k < NRBF; k++) fg = fmaf(sh_rbf[m0 + m][k], wf[k], fg);
            aval[m] = fg * sh_ccut[m0 + m] * (acc[m] + b2t);
        }
    }

    // ---- GEMM2 pass B: cols [256,384) -> scalar message M; pack VM ----
    #pragma unroll
    for (int m = 0; m < TMH; m++) acc[m] = 0.0f;
    for (int k = 0; k < FDIM; k += 4) {
        float w0 = W2[(k + 0) * 384 + 256 + c];
        float w1 = W2[(k + 1) * 384 + 256 + c];
        float w2 = W2[(k + 2) * 384 + 256 + c];
        float w3 = W2[(k + 3) * 384 + 256 + c];
        #pragma unroll
        for (int m = 0; m < TMH; m++) {
            float4 s4 = *(const float4*)&sh_s[m0 + m][k];
            acc[m] = fmaf(s4.x, w0, fmaf(s4.y, w1, fmaf(s4.z, w2, fmaf(s4.w, w3, acc[m]))));
        }
    }
    {
        float wf[NRBF];
        #pragma unroll
        for (int k = 0; k < NRBF; k++) wf[k] = Wf[k * 384 + 256 + c];
        float bft = bf[256 + c];
        float b2t = b2[256 + c];
        #pragma unroll
        for (int m = 0; m < TMH; m++) {
            float fm = bft;
            #pragma unroll
            for (int k = 0; k < NRBF; k++) fm = fmaf(sh_rbf[m0 + m][k], wf[k], fm);
            float mm = fm * sh_ccut[m0 + m] * (acc[m] + b2t);
            int n = n0 + m0 + m;
            const float* vp = node_vec + (size_t)n * 384 + 3 * c;
            float v0 = vp[0], v1 = vp[1], v2 = vp[2];
            float a = aval[m];
            if (use_f32) {
                VMf[(size_t)n * FDIM + c] = make_float4(a * v0, a * v1, a * v2, mm);
            } else {
                ushort4 r;
                r.x = bf16_bits(a * v0);
                r.y = bf16_bits(a * v1);
                r.z = bf16_bits(a * v2);
                r.w = bf16_bits(mm);
                VMh[(size_t)n * FDIM + c] = r;
            }
        }
    }
}

// ---------------- CSR build ------------------------------------------------
__global__ __launch_bounds__(256) void hist_kernel(
    const int* __restrict__ edge, int* __restrict__ counts, int E)
{
    int i = blockIdx.x * 256 + threadIdx.x;
    if (i < E) atomicAdd(&counts[edge[2 * i]], 1);
}

__global__ __launch_bounds__(1024) void scan_kernel(
    const int* __restrict__ counts, int* __restrict__ offsets,
    int* __restrict__ cursor, int N)
{
    __shared__ int sh[1024];
    const int t = threadIdx.x;
    const int chunk = (N + 1023) / 1024;
    const int beg = t * chunk, end = min(beg + chunk, N);

    int local = 0;
    for (int i = beg; i < end; i++) local += counts[i];
    sh[t] = local;
    __syncthreads();
    for (int off = 1; off < 1024; off <<= 1) {
        int v = (t >= off) ? sh[t - off] : 0;
        __syncthreads();
        sh[t] += v;
        __syncthreads();
    }
    int run = sh[t] - local;  // exclusive prefix of this chunk
    for (int i = beg; i < end; i++) {
        offsets[i] = run;
        cursor[i] = run;
        run += counts[i];
    }
    if (t == 1023) offsets[N] = sh[1023];
}

__global__ __launch_bounds__(256) void scatter_kernel(
    const int* __restrict__ edge, int* __restrict__ cursor,
    int* __restrict__ src_sorted, int E)
{
    int i = blockIdx.x * 256 + threadIdx.x;
    if (i >= E) return;
    int d = edge[2 * i];
    int s = edge[2 * i + 1];
    int pos = atomicAdd(&cursor[d], 1);
    src_sorted[pos] = s;
}

// ------- gather: one dst per 128 threads, single dwordx4 stream ------------
__global__ __launch_bounds__(256) void gather_f32(
    const int* __restrict__ offsets, const int* __restrict__ src_sorted,
    const float4* __restrict__ VM, const float* __restrict__ node_vec,
    const float* __restrict__ node_s,
    float* __restrict__ out_vec, float* __restrict__ out_s, int N)
{
    int d = blockIdx.x * 2 + (threadIdx.x >> 7);
    int c = threadIdx.x & 127;
    if (d >= N) return;

    int beg = offsets[d];
    int end = offsets[d + 1];

    float a0 = 0.f, a1 = 0.f, a2 = 0.f, as = 0.f;
    int j = beg;
    for (; j + 3 < end; j += 4) {
        int s0 = src_sorted[j], s1 = src_sorted[j + 1];
        int s2 = src_sorted[j + 2], s3 = src_sorted[j + 3];
        float4 r0 = VM[(size_t)s0 * FDIM + c];
        float4 r1 = VM[(size_t)s1 * FDIM + c];
        float4 r2 = VM[(size_t)s2 * FDIM + c];
        float4 r3 = VM[(size_t)s3 * FDIM + c];
        a0 += (r0.x + r1.x) + (r2.x + r3.x);
        a1 += (r0.y + r1.y) + (r2.y + r3.y);
        a2 += (r0.z + r1.z) + (r2.z + r3.z);
        as += (r0.w + r1.w) + (r2.w + r3.w);
    }
    for (; j < end; j++) {
        float4 r = VM[(size_t)src_sorted[j] * FDIM + c];
        a0 += r.x; a1 += r.y; a2 += r.z; as += r.w;
    }

    out_s[(size_t)d * FDIM + c] = node_s[(size_t)d * FDIM + c] + as;
    const float* ip = node_vec + (size_t)d * 384 + 3 * c;
    float* op = out_vec + (size_t)d * 384 + 3 * c;
    op[0] = ip[0] + a0;
    op[1] = ip[1] + a1;
    op[2] = ip[2] + a2;
}

__global__ __launch_bounds__(256) void gather_bf16(
    const int* __restrict__ offsets, const int* __restrict__ src_sorted,
    const ushort4* __restrict__ VM, const float* __restrict__ node_vec,
    const float* __restrict__ node_s,
    float* __restrict__ out_vec, float* __restrict__ out_s, int N)
{
    int d = blockIdx.x * 2 + (threadIdx.x >> 7);
    int c = threadIdx.x & 127;
    if (d >= N) return;

    int beg = offsets[d];
    int end = offsets[d + 1];

    float a0 = 0.f, a1 = 0.f, a2 = 0.f, as = 0.f;
    int j = beg;
    for (; j + 1 < end; j += 2) {
        ushort4 r0 = VM[(size_t)src_sorted[j] * FDIM + c];
        ushort4 r1 = VM[(size_t)src_sorted[j + 1] * FDIM + c];
        a0 += bf16_f(r0.x) + bf16_f(r1.x);
        a1 += bf16_f(r0.y) + bf16_f(r1.y);
        a2 += bf16_f(r0.z) + bf16_f(r1.z);
        as += bf16_f(r0.w) + bf16_f(r1.w);
    }
    for (; j < end; j++) {
        ushort4 r = VM[(size_t)src_sorted[j] * FDIM + c];
        a0 += bf16_f(r.x); a1 += bf16_f(r.y); a2 += bf16_f(r.z); as += bf16_f(r.w);
    }

    out_s[(size_t)d * FDIM + c] = node_s[(size_t)d * FDIM + c] + as;
    const float* ip = node_vec + (size_t)d * 384 + 3 * c;
    float* op = out_vec + (size_t)d * 384 + 3 * c;
    op[0] = ip[0] + a0;
    op[1] = ip[1] + a1;
    op[2] = ip[2] + a2;
}

extern "C" void kernel_launch(void* const* d_in, const int* in_sizes, int n_in,
                              void* d_out, int out_size, void* d_ws, size_t ws_size,
                              hipStream_t stream) {
    const float* node_s   = (const float*)d_in[0];
    const float* node_vec = (const float*)d_in[1];
    const int*   edge     = (const int*)d_in[2];
    const float* edge_dis = (const float*)d_in[4];
    const float* W1 = (const float*)d_in[5];
    const float* b1 = (const float*)d_in[6];
    const float* W2 = (const float*)d_in[7];
    const float* b2 = (const float*)d_in[8];
    const float* Wf = (const float*)d_in[9];
    const float* bf = (const float*)d_in[10];

    const int N = in_sizes[0] / FDIM;
    const int E = in_sizes[2] / 2;

    float* out_vec = (float*)d_out;              // N*128*3
    float* out_s   = out_vec + (size_t)N * 384;  // N*128

    // workspace: ints first, then VM (16B-aligned)
    int* counts     = (int*)d_ws;          // N
    int* offsets    = counts + N;          // N+1
    int* cursor     = offsets + N + 1;     // N
    int* src_sorted = cursor + N;          // E
    size_t int_bytes = (((size_t)(3 * N + 1 + E) * 4) + 15) & ~(size_t)15;
    void* vm_base = (char*)d_ws + int_bytes;

    size_t need_f32 = int_bytes + (size_t)N * FDIM * sizeof(float4);
    int use_f32 = (ws_size >= need_f32) ? 1 : 0;
    float4*  VMf = (float4*)vm_base;
    ushort4* VMh = (ushort4*)vm_base;

    hipMemsetAsync(counts, 0, (size_t)N * sizeof(int), stream);

    node_kernel<<<(N + TMB - 1) / TMB, 256, 0, stream>>>(
        node_s, node_vec, edge_dis, W1, b1, W2, b2, Wf, bf, VMf, VMh, use_f32, N);

    hist_kernel<<<(E + 255) / 256, 256, 0, stream>>>(edge, counts, E);
    scan_kernel<<<1, 1024, 0, stream>>>(counts, offsets, cursor, N);
    scatter_kernel<<<(E + 255) / 256, 256, 0, stream>>>(edge, cursor, src_sorted, E);

    if (use_f32) {
        gather_f32<<<(N + 1) / 2, 256, 0, stream>>>(
            offsets, src_sorted, VMf, node_vec, node_s, out_vec, out_s, N);
    } else {
        gather_bf16<<<(N + 1) / 2, 256, 0, stream>>>(
            offsets, src_sorted, VMh, node_vec, node_s, out_vec, out_s, N);
    }
}